// Round 4
// baseline (224.647 us; speedup 1.0000x reference)
//
#include <hip/hip_runtime.h>
#include <math.h>

#define N 8192
#define FIN 128
#define FOUT 64
#define ALPHA 0.2f

typedef __attribute__((ext_vector_type(8))) short bf16x8;
typedef __attribute__((ext_vector_type(8))) unsigned short ushort8;
typedef __attribute__((ext_vector_type(4))) float f32x4;

__device__ __forceinline__ unsigned short f2bf(float f) {
    unsigned int u = __float_as_uint(f);
    u += 0x7fff + ((u >> 16) & 1);          // round-to-nearest-even
    return (unsigned short)(u >> 16);
}
__device__ __forceinline__ float elu(float v) { return v > 0.f ? v : expm1f(v); }
__device__ __forceinline__ unsigned fenc(float f) {
    unsigned u = __float_as_uint(f);
    return (u & 0x80000000u) ? ~u : (u | 0x80000000u);   // monotone float->uint
}

// ---------------- Kernel A: h = x @ W, fused s1/s2/s2max ----------------
__global__ __launch_bounds__(256) void k_h(const float* __restrict__ x,
                                           const float* __restrict__ W,
                                           const float* __restrict__ a,
                                           float* __restrict__ h,
                                           float* __restrict__ s1,
                                           float* __restrict__ s2,
                                           unsigned* __restrict__ s2me) {
    __shared__ float Wl[FIN * FOUT];
    int t = threadIdx.x;
    #pragma unroll
    for (int i = 0; i < (FIN * FOUT) / (256 * 4); ++i) {
        int idx = (t + i * 256) * 4;
        *(float4*)&Wl[idx] = *(const float4*)&W[idx];
    }
    __syncthreads();
    int gid = blockIdx.x * 256 + t;
    int row = gid >> 6;
    int c   = gid & 63;
    float acc = 0.f;
    #pragma unroll
    for (int k = 0; k < FIN; k += 4) {
        float4 xv = *(const float4*)&x[row * FIN + k];
        acc = fmaf(xv.x, Wl[(k + 0) * FOUT + c], acc);
        acc = fmaf(xv.y, Wl[(k + 1) * FOUT + c], acc);
        acc = fmaf(xv.z, Wl[(k + 2) * FOUT + c], acc);
        acc = fmaf(xv.w, Wl[(k + 3) * FOUT + c], acc);
    }
    h[gid] = acc;
    float p1 = acc * a[c];
    float p2 = acc * a[64 + c];
    #pragma unroll
    for (int off = 32; off; off >>= 1) {
        p1 += __shfl_xor(p1, off);
        p2 += __shfl_xor(p2, off);
    }
    if (c == 0) {
        s1[row] = p1;
        s2[row] = p2;
        atomicMax(s2me, fenc(p2));   // order-independent -> deterministic
    }
}

// ---------------- Kernel T: hT[c][j] = bf16(h[j][c])  (64 x 8192) ----------------
__global__ __launch_bounds__(256) void k_t(const float* __restrict__ h,
                                           unsigned short* __restrict__ hT) {
    __shared__ float tile[64][65];
    int t = threadIdx.x;
    int j0 = blockIdx.x * 64;
    #pragma unroll
    for (int p = 0; p < 4; ++p) {
        int j = p * 16 + (t >> 4);
        int c4 = (t & 15) * 4;
        float4 v = *(const float4*)&h[(size_t)(j0 + j) * 64 + c4];
        tile[j][c4] = v.x; tile[j][c4 + 1] = v.y; tile[j][c4 + 2] = v.z; tile[j][c4 + 3] = v.w;
    }
    __syncthreads();
    int c = t & 63, seg = t >> 6;
    ushort8 u0, u1;
    #pragma unroll
    for (int k = 0; k < 8; ++k) u0[k] = f2bf(tile[seg * 16 + k][c]);
    #pragma unroll
    for (int k = 0; k < 8; ++k) u1[k] = f2bf(tile[seg * 16 + 8 + k][c]);
    unsigned short* dst = &hT[(size_t)c * N + j0 + seg * 16];
    *(ushort8*)dst = u0;
    *(ushort8*)(dst + 8) = u1;
}

// ---------------- Kernel D: masked softmax + attention @ h via MFMA ----------------
// 1 wave = 16 rows x 64 cols. Lane l computes A-frag w[l&15][(l>>4)*8+i] directly.
// Register double-buffer: adj/s2 for iter i+1 issued while computing iter i.
// launch_bounds (256,4): VGPR cap 128 -- (256,6) forced spill, +90us (round 3).
template <int JS>
__global__ __launch_bounds__(256, 4) void k_attn(const float* __restrict__ adj,
                                                 const unsigned short* __restrict__ hT,
                                                 const float* __restrict__ s1,
                                                 const float* __restrict__ s2,
                                                 const unsigned* __restrict__ s2me,
                                                 float* __restrict__ pacc,
                                                 float* __restrict__ pden,
                                                 float* __restrict__ out) {
    const int JLEN = N / JS;
    int wave = threadIdx.x >> 6;
    int lane = threadIdx.x & 63;
    int rt   = (blockIdx.x / JS) * 4 + wave;   // row tile [0, 512)
    int js   = blockIdx.x % JS;
    int r0   = rt * 16;
    int jb   = js * JLEN;

    int row = lane & 15;
    int kg  = lane >> 4;
    int r   = r0 + row;

    float s1v = s1[r];
    unsigned em = *s2me;
    float S2M = __uint_as_float((em & 0x80000000u) ? (em & 0x7fffffffu) : ~em);
    float pM  = s1v + S2M;
    float Mv  = fmaxf(pM, ALPHA * pM);   // lrelu monotone: >= any e in row

    f32x4 acc0 = {0.f, 0.f, 0.f, 0.f};
    f32x4 acc1 = {0.f, 0.f, 0.f, 0.f};
    f32x4 acc2 = {0.f, 0.f, 0.f, 0.f};
    f32x4 acc3 = {0.f, 0.f, 0.f, 0.f};
    float den = 0.f;

    const size_t rbase = (size_t)r * N;
    const unsigned short* hb = hT + (size_t)row * N;

    int jp = jb + kg * 8;
    float4 na0 = *(const float4*)&adj[rbase + jp];
    float4 na1 = *(const float4*)&adj[rbase + jp + 4];
    float4 ns0 = *(const float4*)&s2[jp];
    float4 ns1 = *(const float4*)&s2[jp + 4];

    for (int j0 = jb; j0 < jb + JLEN; j0 += 32) {
        float4 a0 = na0, a1 = na1, t0 = ns0, t1 = ns1;
        int jc  = j0 + kg * 8;
        int j0n = (j0 + 32 < jb + JLEN) ? j0 + 32 : jb;
        int jn  = j0n + kg * 8;
        na0 = *(const float4*)&adj[rbase + jn];
        na1 = *(const float4*)&adj[rbase + jn + 4];
        ns0 = *(const float4*)&s2[jn];
        ns1 = *(const float4*)&s2[jn + 4];

        float av[8] = {a0.x, a0.y, a0.z, a0.w, a1.x, a1.y, a1.z, a1.w};
        float sv[8] = {t0.x, t0.y, t0.z, t0.w, t1.x, t1.y, t1.z, t1.w};

        union { bf16x8 v; unsigned short u[8]; } af;
        #pragma unroll
        for (int i = 0; i < 8; ++i) {
            float pre = s1v + sv[i];
            float e   = fmaxf(pre, ALPHA * pre);
            float w   = av[i] * __expf(e - Mv);   // av in {0,1}: mask by multiply
            den += w;
            af.u[i] = f2bf(w);
        }

        bf16x8 b0 = *(const bf16x8*)&hb[(size_t)(0 * 16) * N + jc];
        bf16x8 b1 = *(const bf16x8*)&hb[(size_t)(1 * 16) * N + jc];
        bf16x8 b2 = *(const bf16x8*)&hb[(size_t)(2 * 16) * N + jc];
        bf16x8 b3 = *(const bf16x8*)&hb[(size_t)(3 * 16) * N + jc];
        acc0 = __builtin_amdgcn_mfma_f32_16x16x32_bf16(af.v, b0, acc0, 0, 0, 0);
        acc1 = __builtin_amdgcn_mfma_f32_16x16x32_bf16(af.v, b1, acc1, 0, 0, 0);
        acc2 = __builtin_amdgcn_mfma_f32_16x16x32_bf16(af.v, b2, acc2, 0, 0, 0);
        acc3 = __builtin_amdgcn_mfma_f32_16x16x32_bf16(af.v, b3, acc3, 0, 0, 0);
    }

    den += __shfl_xor(den, 16);
    den += __shfl_xor(den, 32);

    #pragma unroll
    for (int q = 0; q < 4; ++q) {
        int ro = kg * 4 + q;
        float d = __shfl(den, ro);
        float v0 = acc0[q], v1 = acc1[q], v2 = acc2[q], v3 = acc3[q];
        if (JS == 1) {
            size_t ob = (size_t)(r0 + ro) * 64 + row;
            out[ob + 0]  = elu(v0 / d);
            out[ob + 16] = elu(v1 / d);
            out[ob + 32] = elu(v2 / d);
            out[ob + 48] = elu(v3 / d);
        } else {
            size_t ob = ((size_t)js * N + r0 + ro) * 64 + row;
            pacc[ob + 0]  = v0;
            pacc[ob + 16] = v1;
            pacc[ob + 32] = v2;
            pacc[ob + 48] = v3;
        }
    }
    if (JS > 1 && lane < 16) pden[(size_t)js * N + r0 + lane] = den;
}

// ---------------- Kernel E: combine partials, div + elu ----------------
template <int JS>
__global__ __launch_bounds__(256) void k_combine(const float* __restrict__ pacc,
                                                 const float* __restrict__ pden,
                                                 float* __restrict__ out) {
    int gid = blockIdx.x * 256 + threadIdx.x;
    int row = gid >> 6;
    float a = 0.f, d = 0.f;
    #pragma unroll
    for (int s = 0; s < JS; ++s) {
        a += pacc[((size_t)s * N + row) * 64 + (gid & 63)];
        d += pden[(size_t)s * N + row];
    }
    out[gid] = elu(a / d);
}

// ---------------- launch ----------------
extern "C" void kernel_launch(void* const* d_in, const int* in_sizes, int n_in,
                              void* d_out, int out_size, void* d_ws, size_t ws_size,
                              hipStream_t stream) {
    const float* x   = (const float*)d_in[0];
    const float* adj = (const float*)d_in[1];
    const float* W   = (const float*)d_in[2];
    const float* a   = (const float*)d_in[3];
    float* out = (float*)d_out;

    // ws layout (floats)
    float* ws   = (float*)d_ws;
    float* h    = ws;                               // 524288
    float* s1   = h + (size_t)N * FOUT;             // 8192
    float* s2   = s1 + N;                           // 8192
    unsigned* s2me = (unsigned*)(s2 + N);           // 64 slot
    float* pden = (float*)s2me + 64;                // 16*8192
    unsigned short* hT = (unsigned short*)(pden + 16 * N);   // 262144 floats
    float* pacc = (float*)hT + 262144;              // JS*524288

    size_t fixed = 524288 + 8192 + 8192 + 64 + 16 * (size_t)N + 262144;
    int js = 1;
    if      (ws_size >= (fixed + 16 * 524288ull) * 4) js = 16;
    else if (ws_size >= (fixed + 8  * 524288ull) * 4) js = 8;
    else if (ws_size >= (fixed + 4  * 524288ull) * 4) js = 4;
    else if (ws_size >= (fixed + 2  * 524288ull) * 4) js = 2;

    hipMemsetAsync(s2me, 0, sizeof(unsigned), stream);   // fenc lower bound
    k_h<<<dim3((N * FOUT) / 256), dim3(256), 0, stream>>>(x, W, a, h, s1, s2, s2me);
    k_t<<<dim3(N / 64), dim3(256), 0, stream>>>(h, hT);

    switch (js) {
        case 16:
            k_attn<16><<<dim3(128 * 16), dim3(256), 0, stream>>>(adj, hT, s1, s2, s2me, pacc, pden, out);
            k_combine<16><<<dim3((N * FOUT) / 256), dim3(256), 0, stream>>>(pacc, pden, out);
            break;
        case 8:
            k_attn<8><<<dim3(128 * 8), dim3(256), 0, stream>>>(adj, hT, s1, s2, s2me, pacc, pden, out);
            k_combine<8><<<dim3((N * FOUT) / 256), dim3(256), 0, stream>>>(pacc, pden, out);
            break;
        case 4:
            k_attn<4><<<dim3(128 * 4), dim3(256), 0, stream>>>(adj, hT, s1, s2, s2me, pacc, pden, out);
            k_combine<4><<<dim3((N * FOUT) / 256), dim3(256), 0, stream>>>(pacc, pden, out);
            break;
        case 2:
            k_attn<2><<<dim3(128 * 2), dim3(256), 0, stream>>>(adj, hT, s1, s2, s2me, pacc, pden, out);
            k_combine<2><<<dim3((N * FOUT) / 256), dim3(256), 0, stream>>>(pacc, pden, out);
            break;
        default:
            k_attn<1><<<dim3(128), dim3(256), 0, stream>>>(adj, hT, s1, s2, s2me, pacc, pden, out);
            break;
    }
}

// Round 6
// 165.473 us; speedup vs baseline: 1.3576x; 1.3576x over previous
//
#include <hip/hip_runtime.h>
#include <math.h>

#define N 8192
#define FIN 128
#define FOUT 64
#define ALPHA 0.2f

typedef __attribute__((ext_vector_type(8))) short bf16x8;
typedef __attribute__((ext_vector_type(8))) unsigned short ushort8;
typedef __attribute__((ext_vector_type(4))) float f32x4;

__device__ __forceinline__ unsigned short f2bf(float f) {
    unsigned int u = __float_as_uint(f);
    u += 0x7fff + ((u >> 16) & 1);          // round-to-nearest-even
    return (unsigned short)(u >> 16);
}
__device__ __forceinline__ float elu(float v) { return v > 0.f ? v : expm1f(v); }

// ---------------- Kernel P: pack adj -> bitmask (256MB -> 8MB), pure streaming ----------------
__global__ __launch_bounds__(256) void k_pack(const float* __restrict__ adj,
                                              unsigned char* __restrict__ mask) {
    const size_t G = (size_t)N * N / 8;               // 8M byte-groups
    size_t g = (size_t)blockIdx.x * 256 + threadIdx.x;
    const size_t stride = (size_t)2048 * 256;
    for (; g < G; g += stride) {
        const float* p = adj + g * 8;
        f32x4 v0 = __builtin_nontemporal_load((const f32x4*)p);
        f32x4 v1 = __builtin_nontemporal_load((const f32x4*)(p + 4));
        unsigned m =  (unsigned)(v0[0] != 0.f)
                   | ((unsigned)(v0[1] != 0.f) << 1)
                   | ((unsigned)(v0[2] != 0.f) << 2)
                   | ((unsigned)(v0[3] != 0.f) << 3)
                   | ((unsigned)(v1[0] != 0.f) << 4)
                   | ((unsigned)(v1[1] != 0.f) << 5)
                   | ((unsigned)(v1[2] != 0.f) << 6)
                   | ((unsigned)(v1[3] != 0.f) << 7);
        mask[g] = (unsigned char)m;
    }
}

// ---------------- Kernel A: h = x @ W, fused s1/s2 epilogue ----------------
__global__ __launch_bounds__(256) void k_h(const float* __restrict__ x,
                                           const float* __restrict__ W,
                                           const float* __restrict__ a,
                                           float* __restrict__ h,
                                           float* __restrict__ s1,
                                           float* __restrict__ s2) {
    __shared__ float Wl[FIN * FOUT];
    int t = threadIdx.x;
    #pragma unroll
    for (int i = 0; i < (FIN * FOUT) / (256 * 4); ++i) {
        int idx = (t + i * 256) * 4;
        *(float4*)&Wl[idx] = *(const float4*)&W[idx];
    }
    __syncthreads();
    int gid = blockIdx.x * 256 + t;
    int row = gid >> 6;
    int c   = gid & 63;
    float acc = 0.f;
    #pragma unroll
    for (int k = 0; k < FIN; k += 4) {
        float4 xv = *(const float4*)&x[row * FIN + k];
        acc = fmaf(xv.x, Wl[(k + 0) * FOUT + c], acc);
        acc = fmaf(xv.y, Wl[(k + 1) * FOUT + c], acc);
        acc = fmaf(xv.z, Wl[(k + 2) * FOUT + c], acc);
        acc = fmaf(xv.w, Wl[(k + 3) * FOUT + c], acc);
    }
    h[gid] = acc;
    float p1 = acc * a[c];
    float p2 = acc * a[64 + c];
    #pragma unroll
    for (int off = 32; off; off >>= 1) {
        p1 += __shfl_xor(p1, off);
        p2 += __shfl_xor(p2, off);
    }
    if (c == 0) { s1[row] = p1; s2[row] = p2; }
}

// ---------------- Kernel C: S2MAX = max(s2) ----------------
__global__ __launch_bounds__(256) void k_max(const float* __restrict__ s2,
                                             float* __restrict__ s2max) {
    __shared__ float red[256];
    float m = -1e30f;
    for (int i = threadIdx.x; i < N; i += 256) m = fmaxf(m, s2[i]);
    red[threadIdx.x] = m;
    __syncthreads();
    #pragma unroll
    for (int s = 128; s; s >>= 1) {
        if (threadIdx.x < s) red[threadIdx.x] = fmaxf(red[threadIdx.x], red[threadIdx.x + s]);
        __syncthreads();
    }
    if (threadIdx.x == 0) *s2max = red[0];
}

// ---------------- Kernel T: hT[c][j] = bf16(h[j][c])  (64 x 8192) ----------------
__global__ __launch_bounds__(256) void k_t(const float* __restrict__ h,
                                           unsigned short* __restrict__ hT) {
    __shared__ float tile[64][65];
    int t = threadIdx.x;
    int j0 = blockIdx.x * 64;
    #pragma unroll
    for (int p = 0; p < 4; ++p) {
        int j = p * 16 + (t >> 4);
        int c4 = (t & 15) * 4;
        float4 v = *(const float4*)&h[(size_t)(j0 + j) * 64 + c4];
        tile[j][c4] = v.x; tile[j][c4 + 1] = v.y; tile[j][c4 + 2] = v.z; tile[j][c4 + 3] = v.w;
    }
    __syncthreads();
    int c = t & 63, seg = t >> 6;
    ushort8 u0, u1;
    #pragma unroll
    for (int k = 0; k < 8; ++k) u0[k] = f2bf(tile[seg * 16 + k][c]);
    #pragma unroll
    for (int k = 0; k < 8; ++k) u1[k] = f2bf(tile[seg * 16 + 8 + k][c]);
    unsigned short* dst = &hT[(size_t)c * N + j0 + seg * 16];
    *(ushort8*)dst = u0;
    *(ushort8*)(dst + 8) = u1;
}

// ---------------- Kernel D: masked softmax + attention @ h via MFMA ----------------
// 1 wave = 16 rows x 64 cols. Lane l computes A-frag w[l&15][(l>>4)*8+i] directly.
// adj replaced by 8MB L2/L3-resident bitmask: 1 byte/lane/iter.
// NO register prefetch: VGPR ~64 -> 8 waves/SIMD is the latency-hiding resource
// (round 3/4 lesson: prefetch regs cost 3 waves/SIMD, net -90us).
template <int JS>
__global__ __launch_bounds__(256, 4) void k_attn(const unsigned char* __restrict__ mask,
                                                 const unsigned short* __restrict__ hT,
                                                 const float* __restrict__ s1,
                                                 const float* __restrict__ s2,
                                                 const float* __restrict__ s2max,
                                                 float* __restrict__ pacc,
                                                 float* __restrict__ pden,
                                                 float* __restrict__ out) {
    const int JLEN = N / JS;
    int wave = threadIdx.x >> 6;
    int lane = threadIdx.x & 63;
    int rt   = (blockIdx.x / JS) * 4 + wave;   // row tile [0, 512)
    int js   = blockIdx.x % JS;
    int r0   = rt * 16;
    int jb   = js * JLEN;

    int row = lane & 15;
    int kg  = lane >> 4;
    int r   = r0 + row;

    float s1v = s1[r];
    float S2M = *s2max;
    float pM  = s1v + S2M;
    float Mv  = fmaxf(pM, ALPHA * pM);   // lrelu monotone: >= any e in row

    f32x4 acc0 = {0.f, 0.f, 0.f, 0.f};
    f32x4 acc1 = {0.f, 0.f, 0.f, 0.f};
    f32x4 acc2 = {0.f, 0.f, 0.f, 0.f};
    f32x4 acc3 = {0.f, 0.f, 0.f, 0.f};
    float den = 0.f;

    const size_t rbase8 = (size_t)r * (N / 8);
    const unsigned short* hb = hT + (size_t)row * N;

    for (int j0 = jb; j0 < jb + JLEN; j0 += 32) {
        int jj = j0 + kg * 8;
        unsigned mb = mask[rbase8 + (j0 >> 3) + kg];
        float4 t0 = *(const float4*)&s2[jj];
        float4 t1 = *(const float4*)&s2[jj + 4];

        float sv[8] = {t0.x, t0.y, t0.z, t0.w, t1.x, t1.y, t1.z, t1.w};

        union { bf16x8 v; unsigned short u[8]; } af;
        #pragma unroll
        for (int i = 0; i < 8; ++i) {
            float pre = s1v + sv[i];
            float e   = fmaxf(pre, ALPHA * pre);
            float ex  = __expf(e - Mv);
            float w   = (mb & (1u << i)) ? ex : 0.f;   // v_cndmask
            den += w;
            af.u[i] = f2bf(w);
        }

        bf16x8 b0 = *(const bf16x8*)&hb[(size_t)(0 * 16) * N + jj];
        bf16x8 b1 = *(const bf16x8*)&hb[(size_t)(1 * 16) * N + jj];
        bf16x8 b2 = *(const bf16x8*)&hb[(size_t)(2 * 16) * N + jj];
        bf16x8 b3 = *(const bf16x8*)&hb[(size_t)(3 * 16) * N + jj];
        acc0 = __builtin_amdgcn_mfma_f32_16x16x32_bf16(af.v, b0, acc0, 0, 0, 0);
        acc1 = __builtin_amdgcn_mfma_f32_16x16x32_bf16(af.v, b1, acc1, 0, 0, 0);
        acc2 = __builtin_amdgcn_mfma_f32_16x16x32_bf16(af.v, b2, acc2, 0, 0, 0);
        acc3 = __builtin_amdgcn_mfma_f32_16x16x32_bf16(af.v, b3, acc3, 0, 0, 0);
    }

    den += __shfl_xor(den, 16);
    den += __shfl_xor(den, 32);

    #pragma unroll
    for (int q = 0; q < 4; ++q) {
        int ro = kg * 4 + q;
        float d = __shfl(den, ro);
        float v0 = acc0[q], v1 = acc1[q], v2 = acc2[q], v3 = acc3[q];
        if (JS == 1) {
            size_t ob = (size_t)(r0 + ro) * 64 + row;
            out[ob + 0]  = elu(v0 / d);
            out[ob + 16] = elu(v1 / d);
            out[ob + 32] = elu(v2 / d);
            out[ob + 48] = elu(v3 / d);
        } else {
            size_t ob = ((size_t)js * N + r0 + ro) * 64 + row;
            pacc[ob + 0]  = v0;
            pacc[ob + 16] = v1;
            pacc[ob + 32] = v2;
            pacc[ob + 48] = v3;
        }
    }
    if (JS > 1 && lane < 16) pden[(size_t)js * N + r0 + lane] = den;
}

// ---------------- Kernel E: combine partials, div + elu ----------------
template <int JS>
__global__ __launch_bounds__(256) void k_combine(const float* __restrict__ pacc,
                                                 const float* __restrict__ pden,
                                                 float* __restrict__ out) {
    int gid = blockIdx.x * 256 + threadIdx.x;
    int row = gid >> 6;
    float a = 0.f, d = 0.f;
    #pragma unroll
    for (int s = 0; s < JS; ++s) {
        a += pacc[((size_t)s * N + row) * 64 + (gid & 63)];
        d += pden[(size_t)s * N + row];
    }
    out[gid] = elu(a / d);
}

// ---------------- launch ----------------
extern "C" void kernel_launch(void* const* d_in, const int* in_sizes, int n_in,
                              void* d_out, int out_size, void* d_ws, size_t ws_size,
                              hipStream_t stream) {
    const float* x   = (const float*)d_in[0];
    const float* adj = (const float*)d_in[1];
    const float* W   = (const float*)d_in[2];
    const float* a   = (const float*)d_in[3];
    float* out = (float*)d_out;

    // ws layout (float units)
    float* ws   = (float*)d_ws;
    float* h    = ws;                                // 524288
    float* s1   = h + (size_t)N * FOUT;              // 8192
    float* s2   = s1 + N;                            // 8192
    float* s2m  = s2 + N;                            // 64
    float* pden = s2m + 64;                          // 8*8192
    unsigned short* hT = (unsigned short*)(pden + 8 * N);    // 262144 float-equiv
    unsigned char* mask = (unsigned char*)((float*)hT + 262144); // 8MB = 2097152 float-equiv
    float* pacc = (float*)hT + 262144 + 2097152;     // 8*524288

    size_t fixed = 524288 + 8192 + 8192 + 64 + 8 * (size_t)N + 262144 + 2097152;
    int js = (ws_size >= (fixed + 8 * 524288ull) * 4) ? 8 : 1;

    k_pack<<<dim3(2048), dim3(256), 0, stream>>>(adj, mask);
    k_h<<<dim3((N * FOUT) / 256), dim3(256), 0, stream>>>(x, W, a, h, s1, s2);
    k_max<<<dim3(1), dim3(256), 0, stream>>>(s2, s2m);
    k_t<<<dim3(N / 64), dim3(256), 0, stream>>>(h, hT);

    if (js == 8) {
        k_attn<8><<<dim3(128 * 8), dim3(256), 0, stream>>>(mask, hT, s1, s2, s2m, pacc, pden, out);
        k_combine<8><<<dim3((N * FOUT) / 256), dim3(256), 0, stream>>>(pacc, pden, out);
    } else {
        k_attn<1><<<dim3(128), dim3(256), 0, stream>>>(mask, hT, s1, s2, s2m, pacc, pden, out);
    }
}

// Round 7
// 142.220 us; speedup vs baseline: 1.5796x; 1.1635x over previous
//
#include <hip/hip_runtime.h>
#include <math.h>

#define N 8192
#define FIN 128
#define FOUT 64
#define ALPHA 0.2f

typedef __attribute__((ext_vector_type(8))) short bf16x8;
typedef __attribute__((ext_vector_type(8))) unsigned short ushort8;
typedef __attribute__((ext_vector_type(4))) float f32x4;

__device__ __forceinline__ unsigned short f2bf(float f) {
    unsigned int u = __float_as_uint(f);
    u += 0x7fff + ((u >> 16) & 1);          // round-to-nearest-even
    return (unsigned short)(u >> 16);
}
__device__ __forceinline__ float elu(float v) { return v > 0.f ? v : expm1f(v); }

// ---------------- Kernel A: h = x @ W, fused s1/s2 epilogue ----------------
__global__ __launch_bounds__(256) void k_h(const float* __restrict__ x,
                                           const float* __restrict__ W,
                                           const float* __restrict__ a,
                                           float* __restrict__ h,
                                           float* __restrict__ s1,
                                           float* __restrict__ s2) {
    __shared__ float Wl[FIN * FOUT];
    int t = threadIdx.x;
    #pragma unroll
    for (int i = 0; i < (FIN * FOUT) / (256 * 4); ++i) {
        int idx = (t + i * 256) * 4;
        *(float4*)&Wl[idx] = *(const float4*)&W[idx];
    }
    __syncthreads();
    int gid = blockIdx.x * 256 + t;
    int row = gid >> 6;
    int c   = gid & 63;
    float acc = 0.f;
    #pragma unroll
    for (int k = 0; k < FIN; k += 4) {
        float4 xv = *(const float4*)&x[row * FIN + k];
        acc = fmaf(xv.x, Wl[(k + 0) * FOUT + c], acc);
        acc = fmaf(xv.y, Wl[(k + 1) * FOUT + c], acc);
        acc = fmaf(xv.z, Wl[(k + 2) * FOUT + c], acc);
        acc = fmaf(xv.w, Wl[(k + 3) * FOUT + c], acc);
    }
    h[gid] = acc;
    float p1 = acc * a[c];
    float p2 = acc * a[64 + c];
    #pragma unroll
    for (int off = 32; off; off >>= 1) {
        p1 += __shfl_xor(p1, off);
        p2 += __shfl_xor(p2, off);
    }
    if (c == 0) { s1[row] = p1; s2[row] = p2; }
}

// ---------------- Kernel C: S2MAX = max(s2) ----------------
__global__ __launch_bounds__(256) void k_max(const float* __restrict__ s2,
                                             float* __restrict__ s2max) {
    __shared__ float red[256];
    float m = -1e30f;
    for (int i = threadIdx.x; i < N; i += 256) m = fmaxf(m, s2[i]);
    red[threadIdx.x] = m;
    __syncthreads();
    #pragma unroll
    for (int s = 128; s; s >>= 1) {
        if (threadIdx.x < s) red[threadIdx.x] = fmaxf(red[threadIdx.x], red[threadIdx.x + s]);
        __syncthreads();
    }
    if (threadIdx.x == 0) *s2max = red[0];
}

// ---------------- Kernel T: hT[c][j] = bf16(h[j][c])  (64 x 8192) ----------------
__global__ __launch_bounds__(256) void k_t(const float* __restrict__ h,
                                           unsigned short* __restrict__ hT) {
    __shared__ float tile[64][65];
    int t = threadIdx.x;
    int j0 = blockIdx.x * 64;
    #pragma unroll
    for (int p = 0; p < 4; ++p) {
        int j = p * 16 + (t >> 4);
        int c4 = (t & 15) * 4;
        float4 v = *(const float4*)&h[(size_t)(j0 + j) * 64 + c4];
        tile[j][c4] = v.x; tile[j][c4 + 1] = v.y; tile[j][c4 + 2] = v.z; tile[j][c4 + 3] = v.w;
    }
    __syncthreads();
    int c = t & 63, seg = t >> 6;
    ushort8 u0, u1;
    #pragma unroll
    for (int k = 0; k < 8; ++k) u0[k] = f2bf(tile[seg * 16 + k][c]);
    #pragma unroll
    for (int k = 0; k < 8; ++k) u1[k] = f2bf(tile[seg * 16 + 8 + k][c]);
    unsigned short* dst = &hT[(size_t)c * N + j0 + seg * 16];
    *(ushort8*)dst = u0;
    *(ushort8*)(dst + 8) = u1;
}

// ---------------- Kernel D: masked softmax + attention @ h via MFMA ----------------
// 1 wave = 16 rows x 64 cols. Lane l computes A-frag w[l&15][(l>>4)*8+i] directly.
// Occupancy is the latency-hiding resource: VGPR<=64 (launch_bounds 256,8) and
// grid = 8 blocks/CU (JS=16) -> 32 waves/CU. No register prefetch (r3/r4 lesson),
// no bitmask pack (r6 lesson: attn was never adj-BW-bound; pack cost +45us).
template <int JS>
__global__ __launch_bounds__(256, 8) void k_attn(const float* __restrict__ adj,
                                                 const unsigned short* __restrict__ hT,
                                                 const float* __restrict__ s1,
                                                 const float* __restrict__ s2,
                                                 const float* __restrict__ s2max,
                                                 float* __restrict__ pacc,
                                                 float* __restrict__ pden,
                                                 float* __restrict__ out) {
    const int JLEN = N / JS;
    int wave = threadIdx.x >> 6;
    int lane = threadIdx.x & 63;
    int rt   = (blockIdx.x / JS) * 4 + wave;   // row tile [0, 512)
    int js   = blockIdx.x % JS;
    int r0   = rt * 16;
    int jb   = js * JLEN;

    int row = lane & 15;
    int kg  = lane >> 4;
    int r   = r0 + row;

    float s1v = s1[r];
    float S2M = *s2max;
    float pM  = s1v + S2M;
    float Mv  = fmaxf(pM, ALPHA * pM);   // lrelu monotone: >= any e in row

    f32x4 acc0 = {0.f, 0.f, 0.f, 0.f};
    f32x4 acc1 = {0.f, 0.f, 0.f, 0.f};
    f32x4 acc2 = {0.f, 0.f, 0.f, 0.f};
    f32x4 acc3 = {0.f, 0.f, 0.f, 0.f};
    float den = 0.f;

    const size_t rbase = (size_t)r * N;
    const unsigned short* hb = hT + (size_t)row * N;

    for (int j0 = jb; j0 < jb + JLEN; j0 += 32) {
        int jj = j0 + kg * 8;
        float4 a0 = *(const float4*)&adj[rbase + jj];
        float4 a1 = *(const float4*)&adj[rbase + jj + 4];
        float4 t0 = *(const float4*)&s2[jj];
        float4 t1 = *(const float4*)&s2[jj + 4];

        float av[8] = {a0.x, a0.y, a0.z, a0.w, a1.x, a1.y, a1.z, a1.w};
        float sv[8] = {t0.x, t0.y, t0.z, t0.w, t1.x, t1.y, t1.z, t1.w};

        union { bf16x8 v; unsigned short u[8]; } af;
        #pragma unroll
        for (int i = 0; i < 8; ++i) {
            float pre = s1v + sv[i];
            float e   = fmaxf(pre, ALPHA * pre);
            float w   = av[i] * __expf(e - Mv);   // av in {0,1}: mask by multiply
            den += w;
            af.u[i] = f2bf(w);
        }

        bf16x8 b0 = *(const bf16x8*)&hb[(size_t)(0 * 16) * N + jj];
        bf16x8 b1 = *(const bf16x8*)&hb[(size_t)(1 * 16) * N + jj];
        bf16x8 b2 = *(const bf16x8*)&hb[(size_t)(2 * 16) * N + jj];
        bf16x8 b3 = *(const bf16x8*)&hb[(size_t)(3 * 16) * N + jj];
        acc0 = __builtin_amdgcn_mfma_f32_16x16x32_bf16(af.v, b0, acc0, 0, 0, 0);
        acc1 = __builtin_amdgcn_mfma_f32_16x16x32_bf16(af.v, b1, acc1, 0, 0, 0);
        acc2 = __builtin_amdgcn_mfma_f32_16x16x32_bf16(af.v, b2, acc2, 0, 0, 0);
        acc3 = __builtin_amdgcn_mfma_f32_16x16x32_bf16(af.v, b3, acc3, 0, 0, 0);
    }

    den += __shfl_xor(den, 16);
    den += __shfl_xor(den, 32);

    #pragma unroll
    for (int q = 0; q < 4; ++q) {
        int ro = kg * 4 + q;
        float d = __shfl(den, ro);
        float v0 = acc0[q], v1 = acc1[q], v2 = acc2[q], v3 = acc3[q];
        if (JS == 1) {
            size_t ob = (size_t)(r0 + ro) * 64 + row;
            out[ob + 0]  = elu(v0 / d);
            out[ob + 16] = elu(v1 / d);
            out[ob + 32] = elu(v2 / d);
            out[ob + 48] = elu(v3 / d);
        } else {
            size_t ob = ((size_t)js * N + r0 + ro) * 64 + row;
            pacc[ob + 0]  = v0;
            pacc[ob + 16] = v1;
            pacc[ob + 32] = v2;
            pacc[ob + 48] = v3;
        }
    }
    if (JS > 1 && lane < 16) pden[(size_t)js * N + r0 + lane] = den;
}

// ---------------- Kernel E: combine partials, div + elu ----------------
template <int JS>
__global__ __launch_bounds__(256) void k_combine(const float* __restrict__ pacc,
                                                 const float* __restrict__ pden,
                                                 float* __restrict__ out) {
    int gid = blockIdx.x * 256 + threadIdx.x;
    int row = gid >> 6;
    float a = 0.f, d = 0.f;
    #pragma unroll
    for (int s = 0; s < JS; ++s) {
        a += pacc[((size_t)s * N + row) * 64 + (gid & 63)];
        d += pden[(size_t)s * N + row];
    }
    out[gid] = elu(a / d);
}

// ---------------- launch ----------------
extern "C" void kernel_launch(void* const* d_in, const int* in_sizes, int n_in,
                              void* d_out, int out_size, void* d_ws, size_t ws_size,
                              hipStream_t stream) {
    const float* x   = (const float*)d_in[0];
    const float* adj = (const float*)d_in[1];
    const float* W   = (const float*)d_in[2];
    const float* a   = (const float*)d_in[3];
    float* out = (float*)d_out;

    // ws layout (float units)
    float* ws   = (float*)d_ws;
    float* h    = ws;                                // 524288
    float* s1   = h + (size_t)N * FOUT;              // 8192
    float* s2   = s1 + N;                            // 8192
    float* s2m  = s2 + N;                            // 64
    float* pden = s2m + 64;                          // 16*8192 (max JS)
    unsigned short* hT = (unsigned short*)(pden + 16 * N);   // 262144 float-equiv
    float* pacc = (float*)hT + 262144;               // JS*524288

    size_t fixed = 524288 + 8192 + 8192 + 64 + 16 * (size_t)N + 262144;
    int js = 1;
    if      (ws_size >= (fixed + 16 * 524288ull) * 4) js = 16;
    else if (ws_size >= (fixed + 8  * 524288ull) * 4) js = 8;
    else if (ws_size >= (fixed + 4  * 524288ull) * 4) js = 4;

    k_h<<<dim3((N * FOUT) / 256), dim3(256), 0, stream>>>(x, W, a, h, s1, s2);
    k_max<<<dim3(1), dim3(256), 0, stream>>>(s2, s2m);
    k_t<<<dim3(N / 64), dim3(256), 0, stream>>>(h, hT);

    switch (js) {
        case 16:
            k_attn<16><<<dim3(128 * 16), dim3(256), 0, stream>>>(adj, hT, s1, s2, s2m, pacc, pden, out);
            k_combine<16><<<dim3((N * FOUT) / 256), dim3(256), 0, stream>>>(pacc, pden, out);
            break;
        case 8:
            k_attn<8><<<dim3(128 * 8), dim3(256), 0, stream>>>(adj, hT, s1, s2, s2m, pacc, pden, out);
            k_combine<8><<<dim3((N * FOUT) / 256), dim3(256), 0, stream>>>(pacc, pden, out);
            break;
        case 4:
            k_attn<4><<<dim3(128 * 4), dim3(256), 0, stream>>>(adj, hT, s1, s2, s2m, pacc, pden, out);
            k_combine<4><<<dim3((N * FOUT) / 256), dim3(256), 0, stream>>>(pacc, pden, out);
            break;
        default:
            k_attn<1><<<dim3(128), dim3(256), 0, stream>>>(adj, hT, s1, s2, s2m, pacc, pden, out);
            break;
    }
}